// Round 10
// baseline (10517.410 us; speedup 1.0000x reference)
//
#include <hip/hip_runtime.h>
#include <cstdint>

#define NB 128      // batch
#define DH 512      // D == H
#define ROWS 528    // legacy pad stride for h/rh regions

// ---- workspace layout (float offsets) ----
#define OFF_MAR 0u          // [64 chunks][512 k][8 c]   folded r-cols (Wo@Wr+Ur)
#define OFF_MAZ 262144u     // [64 chunks][512 k][24 c]  folded z|gh|out cols
#define OFF_M1R 1048576u    // [64][512][8]              step-1 r-cols (Wr)
#define OFF_M1Z 1310720u    // [64][512][24]             step-1 z|gh|0 cols
#define OFF_UH  2097152u    // [64 chunks][512 k][8 c]   Uh
#define OFF_H   2359296u    // [528][128]  h buffer 0
#define OFF_RH  2426880u    // [528][128]  r*h
#define OFF_XT  2494464u    // [528][128]  inputs^T
#define OFF_GZ  2562048u    // [512][128]  z gate (activated)
#define OFF_GH  2627584u    // [512][128]  pre-h (x-part + bias)
#define OFF_CV  2693120u    // [2048] folded biases (global col order)
#define OFF_C1  2695168u    // [2048] step-1 biases
#define OFF_BAR 2697216u    // 4096 uint32: 3 regions x 8 class lines (128B strided)
#define OFF_H2  2701312u    // [528][128]  h buffer 1

#define BAR_R 0
#define BAR_G 1024
#define BAR_B 2048

__device__ __forceinline__ float sigm(float x) { return 1.f / (1.f + __expf(-x)); }
__device__ __forceinline__ float tanh_fast(float x) {
  float e = __expf(2.f * fminf(x, 40.f));
  return (e - 1.f) / (e + 1.f);
}

// Coherent (agent-scope) access -> global_load/store sc0 sc1: served at the
// coherence point; no cache-wide fences needed anywhere.
__device__ __forceinline__ float cload(const float* p) {
  return __hip_atomic_load(p, __ATOMIC_RELAXED, __HIP_MEMORY_SCOPE_AGENT);
}
__device__ __forceinline__ void cstore(float* p, float v) {
  __hip_atomic_store(p, v, __ATOMIC_RELAXED, __HIP_MEMORY_SCOPE_AGENT);
}

// scatter a folded-matrix element to its role-layout slot
__device__ __forceinline__ void scatterM(float* Mr, float* Mz, int C, int k, float v) {
  if (C < 512) {
    Mr[(C >> 3) * 4096 + k * 8 + (C & 7)] = v;
  } else {
    const int cc = C - 512;
    Mz[(cc / 24) * 12288 + k * 24 + (cc % 24)] = v;
  }
}

// ======================= precompute kernel =======================
__global__ __launch_bounds__(256) void gru_pre(
    const float* __restrict__ inputs,
    const float* __restrict__ Wz, const float* __restrict__ Wr, const float* __restrict__ Wh,
    const float* __restrict__ Uz, const float* __restrict__ Ur, const float* __restrict__ Uh,
    const float* __restrict__ bz, const float* __restrict__ br, const float* __restrict__ bh,
    const float* __restrict__ Wo, const float* __restrict__ bo,
    float* __restrict__ ws)
{
  __shared__ float sh[8960];            // 35 KB scratch, reused per task
  const int bid = blockIdx.x, t = threadIdx.x;
  float* MAr = ws + OFF_MAR;
  float* MAz = ws + OFF_MAZ;
  float* M1r = ws + OFF_M1R;
  float* M1z = ws + OFF_M1Z;
  float* Uhw = ws + OFF_UH;
  float* hw0 = ws + OFF_H;
  float* hw1 = ws + OFF_H2;
  float* rhw = ws + OFF_RH;
  float* xT  = ws + OFF_XT;
  float* cv  = ws + OFF_CV;
  float* c1  = ws + OFF_C1;
  uint32_t* bar = (uint32_t*)(ws + OFF_BAR);

  if (bid < 256) {
    // ---- build M = [Wo@Wr+Ur | Wo@Wz+Uz | Wo@Wh | Wo], scatter to role layouts ----
    const int kh = bid >> 7, cch = bid & 127;
    const int reg = cch >> 5;
    const int k0 = kh * 256, c0 = cch * 16;
    if (reg == 3) {
      const int cc0 = c0 - 1536;
      for (int i = 0; i < 16; ++i) {
        int idx = t + i * 256;
        int kk = k0 + (idx >> 4), ci = idx & 15;
        scatterM(MAr, MAz, c0 + ci, kk, Wo[kk * 512 + cc0 + ci]);
      }
    } else {
      const float* Ws = (reg == 0) ? Wr : (reg == 1) ? Wz : Wh;
      const float* Us = (reg == 0) ? Ur : (reg == 1) ? Uz : nullptr;
      const int cc0 = c0 - reg * 512;
      const int kl = t;
      const int k = k0 + kl;
      float acc[16];
      #pragma unroll
      for (int c = 0; c < 16; ++c) acc[c] = 0.f;
      for (int jt = 0; jt < 16; ++jt) {          // 32-wide j tiles of Wo
        __syncthreads();
        for (int i = 0; i < 32; ++i) {
          int idx = t + i * 256;
          int kk = idx >> 5, jj = idx & 31;
          sh[kk * 35 + jj] = Wo[(k0 + kk) * 512 + jt * 32 + jj];
        }
        __syncthreads();
        for (int j = 0; j < 32; ++j) {
          float wv = sh[kl * 35 + j];
          const float* wrow = Ws + (jt * 32 + j) * 512 + cc0;
          #pragma unroll
          for (int c = 0; c < 16; ++c) acc[c] = fmaf(wv, wrow[c], acc[c]);
        }
      }
      #pragma unroll
      for (int c = 0; c < 16; ++c) {
        float v = acc[c];
        if (Us) v += Us[k * 512 + cc0 + c];
        scatterM(MAr, MAz, c0 + c, k, v);
      }
    }
  }
  else if (bid < 264) {
    // ---- cvec = bo @ W* + b*   (region 3: just bo); global col order ----
    const int q = bid - 256;
    const int r2 = q >> 1;
    const float* Ws = (r2 == 0) ? Wr : (r2 == 1) ? Wz : (r2 == 2) ? Wh : nullptr;
    const float* bs = (r2 == 0) ? br : (r2 == 1) ? bz : (r2 == 2) ? bh : nullptr;
    for (int round = 0; round < 8; ++round) {
      int col32 = t >> 3, strip = t & 7;
      int c = q * 256 + round * 32 + col32;
      int cc = c & 511;
      float p = 0.f;
      if (r2 < 3) {
        for (int j = strip * 64; j < strip * 64 + 64; ++j)
          p = fmaf(bo[j], Ws[j * 512 + cc], p);
      }
      sh[col32 * 8 + strip] = p;
      __syncthreads();
      if (t < 32) {
        float v = 0.f;
        #pragma unroll
        for (int st = 0; st < 8; ++st) v += sh[t * 8 + st];
        int c2 = q * 256 + round * 32 + t;
        int cc2 = c2 & 511;
        cv[c2] = (r2 < 3) ? (v + bs[cc2]) : bo[cc2];
      }
      __syncthreads();
    }
  }
  else if (bid < 296) {
    // ---- M1 = [Wr|Wz|Wh|0] scatter to role layouts ----
    const int q = bid - 264;          // 0..31, 64 cols each
    for (int cq = 0; cq < 64; ++cq) {
      const int C = q * 64 + cq;
      const int r3 = C >> 9;
      const float* Ws = (r3 == 0) ? Wr : (r3 == 1) ? Wz : (r3 == 2) ? Wh : nullptr;
      const int cc = C & 511;
      for (int k = t; k < 512; k += 256) {
        float v = Ws ? Ws[k * 512 + cc] : 0.f;
        scatterM(M1r, M1z, C, k, v);
      }
    }
  }
  else if (bid < 312) {
    // ---- Uh reshape to [64 chunks][512 k][8 c] ----
    const int q = bid - 296;
    for (int cq = 0; cq < 4; ++cq) {
      int ch = q * 4 + cq;
      for (int i = 0; i < 16; ++i) {
        int idx = t + i * 256;
        int kk = idx >> 3, ci = idx & 7;
        Uhw[(ch * 512 + kk) * 8 + ci] = Uh[kk * 512 + ch * 8 + ci];
      }
    }
  }
  else if (bid < 316) {
    // ---- xT = inputs^T (64x64 LDS tiles) ----
    const int q = bid - 312;
    for (int ti = q * 4; ti < q * 4 + 4; ++ti) {
      int bt = ti >> 3, dt = ti & 7;
      __syncthreads();
      for (int i = 0; i < 16; ++i) {
        int idx = t + i * 256;
        int r = idx >> 6, c = idx & 63;
        sh[r * 65 + c] = inputs[(bt * 64 + r) * 512 + dt * 64 + c];
      }
      __syncthreads();
      for (int i = 0; i < 16; ++i) {
        int idx = t + i * 256;
        int r = idx >> 6, c = idx & 63;
        xT[(dt * 64 + r) * 128 + bt * 64 + c] = sh[c * 65 + r];
      }
    }
    if (q == 0) {
      for (int idx = t; idx < 16 * 128; idx += 256) xT[512 * 128 + idx] = 0.f;
    }
  }
  else if (bid == 316) {
    for (int idx = t; idx < ROWS * 128; idx += 256) hw0[idx] = 0.f;    // h buf0 = 0
  }
  else if (bid == 317) {
    for (int idx = t; idx < 16 * 128; idx += 256) rhw[512 * 128 + idx] = 0.f;
  }
  else if (bid == 318) {
    for (int idx = t; idx < 2048; idx += 256)
      c1[idx] = (idx < 512) ? br[idx] : (idx < 1024) ? bz[idx - 512]
              : (idx < 1536) ? bh[idx - 1024] : 0.f;
    for (int idx = t; idx < 4096; idx += 256) bar[idx] = 0u;
  }
  else if (bid == 319) {
    for (int idx = t; idx < ROWS * 128; idx += 256) hw1[idx] = 0.f;    // h buf1 = 0
  }
}

// ============ flat partial barriers: arrive = 1 atomic; wait = poll 8 counters ============
// Release ordering: arrive()'s __syncthreads drains the block's coherent stores.
// Acquire: sc1 loads always read the coherence point. No release hop at all —
// waiters sum the 8 class counters directly (monotonic across steps).
__device__ __forceinline__ void arriveCnt(uint32_t* cnt, int xcls) {
  __syncthreads();
  if (threadIdx.x == 0)
    __hip_atomic_fetch_add(&cnt[xcls * 32], 1u, __ATOMIC_RELAXED, __HIP_MEMORY_SCOPE_AGENT);
}
__device__ __forceinline__ void waitCnt(uint32_t* cnt, uint32_t target) {
  if (threadIdx.x == 0) {
    int guard = 0;
    for (;;) {
      uint32_t ssum = 0;
      #pragma unroll
      for (int x = 0; x < 8; ++x)
        ssum += __hip_atomic_load(&cnt[x * 32], __ATOMIC_RELAXED, __HIP_MEMORY_SCOPE_AGENT);
      if (ssum >= target) break;
      __builtin_amdgcn_s_sleep(1);
      if (++guard > (1 << 18)) break;             // anti-hang: fail fast, absmax will show
    }
  }
  __syncthreads();
}

// ======================= persistent main kernel =======================
// 256 blocks x 512 threads (8 waves), 1 block/CU. Heterogeneous roles:
//  RB (bid 0..127):  A_r (8 r-cols) -> arrive R -> B matmul (8 Uh-cols)
//                    -> [wait G] h-update -> arrive B.   Critical chain.
//  ZB (bid 128..255): A_zgh (24 cols of z|gh|out) -> arrive G -> out stores.
//                    Runs CONCURRENTLY with flag_R + B matmul.
// h double-buffered; flag_B (128 RB arrivals) releases step s+1 for everyone.
// Hazard chain: A*(s+1) gated by flag_B(s); B(s+1) gated by flag_R(s+1) which
// needs RB past flag_B(s) which needs B(s) epilogue past flag_G(s) = all ZB
// h-reads of step s done. So no buffer is overwritten while readable.
__global__ __launch_bounds__(512, 1) void gru_main(
    const float* __restrict__ inputs,
    const float* __restrict__ MAr, const float* __restrict__ MAz,
    const float* __restrict__ M1r, const float* __restrict__ M1z,
    const float* __restrict__ Uhw,
    const float* __restrict__ cvec, const float* __restrict__ c1vec,
    float* __restrict__ hw0, float* __restrict__ hw1,
    float* __restrict__ rhw,
    const float* __restrict__ xT,
    float* __restrict__ Gz, float* __restrict__ Gh,
    uint32_t* __restrict__ bar, float* __restrict__ out, const int T)
{
  __shared__ float Wsh[12288];  // 48 KB: RB: [0:4096)=A-slice, [4096:8192)=Uh; ZB: 24-col slice
  __shared__ float red[6144];   // 24 KB: [4 slots][<=24 c][64 lanes]

  const int bid = blockIdx.x, tid = threadIdx.x;
  const int wave = __builtin_amdgcn_readfirstlane(tid >> 6);  // 0..7, scalar
  const int lane = tid & 63;
  const bool isRB = (bid < 128);
  const int rid  = isRB ? bid : (bid - 128);
  const int half = rid >> 6;                  // batch half 0/1
  const int ch   = rid & 63;                  // col chunk within role
  const int xcls = bid & 7;
  const int b = half * 64 + lane;
  const int cg = tid >> 6, ll = tid & 63;     // epilogue coords
  uint32_t* cntR = bar + BAR_R;
  uint32_t* cntG = bar + BAR_G;
  uint32_t* cntB = bar + BAR_B;

  // ---- initial stage: step-1 weight slices (+Uh for RB) into LDS ----
  if (isRB) {
    const float* s1 = M1r + (size_t)ch * 4096;
    #pragma unroll
    for (int i = 0; i < 2; ++i)
      ((float4*)Wsh)[tid + i * 512] = ((const float4*)s1)[tid + i * 512];
    const float* us = Uhw + (size_t)ch * 4096;
    #pragma unroll
    for (int i = 0; i < 2; ++i)
      ((float4*)(Wsh + 4096))[tid + i * 512] = ((const float4*)us)[tid + i * 512];
  } else {
    const float* s1 = M1z + (size_t)ch * 12288;
    #pragma unroll
    for (int i = 0; i < 6; ++i)
      ((float4*)Wsh)[tid + i * 512] = ((const float4*)s1)[tid + i * 512];
  }
  __syncthreads();

  for (int s = 1; s <= T; ++s) {
    const int p = s & 1;
    const float* hcur = p ? hw1 : hw0;        // s=1 reads hw1 (zeros = h0)
    float* hnxt = p ? hw0 : hw1;
    const float* hsrc = (s == 1) ? xT : hcur;
    const float* cvp = (s == 1) ? c1vec : cvec;
    const uint32_t tgt = (uint32_t)s * 128u;

    if (isRB) {
      // ======== A_r : 8 r-cols ========
      const int C = ch * 8 + cg;              // global r-col, 0..511
      const float hpre = cload(&hcur[C * 128 + half * 64 + ll]);  // h_prev (reused in B)
      float acc[8];
      #pragma unroll
      for (int c = 0; c < 8; ++c) acc[c] = 0.f;
      const float* hp = hsrc + (wave * 64) * 128 + b;
      float hv[32];
      #pragma unroll
      for (int u = 0; u < 32; ++u) hv[u] = cload(hp + u * 128);
      #pragma unroll
      for (int u = 0; u < 32; ++u) {
        const float cur = hv[u];
        hv[u] = cload(hp + (32 + u) * 128);
        const float* mrow = &Wsh[(wave * 64 + u) * 8];
        #pragma unroll
        for (int c = 0; c < 8; ++c) acc[c] = fmaf(cur, mrow[c], acc[c]);
      }
      #pragma unroll
      for (int u = 0; u < 32; ++u) {
        const float* mrow = &Wsh[(wave * 64 + 32 + u) * 8];
        #pragma unroll
        for (int c = 0; c < 8; ++c) acc[c] = fmaf(hv[u], mrow[c], acc[c]);
      }
      if (wave >= 4) {
        #pragma unroll
        for (int c = 0; c < 8; ++c) red[((wave - 4) * 8 + c) * 64 + lane] = acc[c];
      }
      __syncthreads();
      if (wave < 4) {
        #pragma unroll
        for (int c = 0; c < 8; ++c) red[(wave * 8 + c) * 64 + lane] += acc[c];
      }
      __syncthreads();
      float v = red[cg * 64 + ll] + red[512 + cg * 64 + ll]
              + red[1024 + cg * 64 + ll] + red[1536 + cg * 64 + ll] + cvp[C];
      cstore(&rhw[C * 128 + half * 64 + ll], sigm(v) * hpre);
      if (s < T) {
        arriveCnt(cntR, xcls);
        if (s == 1) {             // restage A-slice with folded weights (Uh untouched)
          const float* src = MAr + (size_t)ch * 4096;
          #pragma unroll
          for (int i = 0; i < 2; ++i)
            ((float4*)Wsh)[tid + i * 512] = ((const float4*)src)[tid + i * 512];
        }
        // ======== B : S = rh @ Uh (8 cols) ; h update ========
        waitCnt(cntR, tgt);                   // all rh ready
        float a2[8];
        #pragma unroll
        for (int c = 0; c < 8; ++c) a2[c] = 0.f;
        const float* rp = rhw + (wave * 64) * 128 + b;
        float rv[32];
        #pragma unroll
        for (int u = 0; u < 32; ++u) rv[u] = cload(rp + u * 128);
        #pragma unroll
        for (int u = 0; u < 32; ++u) {
          const float cur = rv[u];
          rv[u] = cload(rp + (32 + u) * 128);
          const float* urow = &Wsh[4096 + (wave * 64 + u) * 8];
          #pragma unroll
          for (int c = 0; c < 8; ++c) a2[c] = fmaf(cur, urow[c], a2[c]);
        }
        #pragma unroll
        for (int u = 0; u < 32; ++u) {
          const float* urow = &Wsh[4096 + (wave * 64 + 32 + u) * 8];
          #pragma unroll
          for (int c = 0; c < 8; ++c) a2[c] = fmaf(rv[u], urow[c], a2[c]);
        }
        if (wave >= 4) {
          #pragma unroll
          for (int c = 0; c < 8; ++c) red[((wave - 4) * 8 + c) * 64 + lane] = a2[c];
        }
        waitCnt(cntG, tgt);                   // Gz/Gh ready (sync doubles as reduce-mid)
        const float zf  = cload(&Gz[C * 128 + half * 64 + ll]);   // issue early,
        const float ghf = cload(&Gh[C * 128 + half * 64 + ll]);   // hide under reduce
        if (wave < 4) {
          #pragma unroll
          for (int c = 0; c < 8; ++c) red[(wave * 8 + c) * 64 + lane] += a2[c];
        }
        __syncthreads();
        const float S = red[cg * 64 + ll] + red[512 + cg * 64 + ll]
                      + red[1024 + cg * 64 + ll] + red[1536 + cg * 64 + ll];
        float hn = (1.f - zf) * hpre + zf * tanh_fast(ghf + S);
        hn = fminf(5.f, fmaxf(-5.f, hn));
        cstore(&hnxt[C * 128 + half * 64 + ll], hn);
        arriveCnt(cntB, xcls);
        waitCnt(cntB, tgt);                   // h(s+1) ready -> next step
      }
    } else {
      // ======== A_zgh : 24 cols of z|gh|out ========
      float acc[24];
      #pragma unroll
      for (int c = 0; c < 24; ++c) acc[c] = 0.f;
      const float* hp = hsrc + (wave * 64) * 128 + b;
      float hv[32];
      #pragma unroll
      for (int u = 0; u < 32; ++u) hv[u] = cload(hp + u * 128);
      #pragma unroll
      for (int u = 0; u < 32; ++u) {
        const float cur = hv[u];
        hv[u] = cload(hp + (32 + u) * 128);
        const float* mrow = &Wsh[(wave * 64 + u) * 24];
        #pragma unroll
        for (int c = 0; c < 24; ++c) acc[c] = fmaf(cur, mrow[c], acc[c]);
      }
      #pragma unroll
      for (int u = 0; u < 32; ++u) {
        const float* mrow = &Wsh[(wave * 64 + 32 + u) * 24];
        #pragma unroll
        for (int c = 0; c < 24; ++c) acc[c] = fmaf(hv[u], mrow[c], acc[c]);
      }
      if (wave >= 4) {
        #pragma unroll
        for (int c = 0; c < 24; ++c) red[((wave - 4) * 24 + c) * 64 + lane] = acc[c];
      }
      __syncthreads();
      if (wave < 4) {
        #pragma unroll
        for (int c = 0; c < 24; ++c) red[(wave * 24 + c) * 64 + lane] += acc[c];
      }
      __syncthreads();
      const int b2 = half * 64 + ll;
      float vo[3]; int Cs[3];
      #pragma unroll
      for (int i = 0; i < 3; ++i) {
        const int cl = cg * 3 + i;           // 0..23
        const int C = 512 + ch * 24 + cl;    // global col 512..2047
        float v = red[cl * 64 + ll] + red[1536 + cl * 64 + ll]
                + red[3072 + cl * 64 + ll] + red[4608 + cl * 64 + ll] + cvp[C];
        vo[i] = v; Cs[i] = C;
        if (C < 1024)      cstore(&Gz[(C - 512) * 128 + b2], sigm(v));
        else if (C < 1536) cstore(&Gh[(C - 1024) * 128 + b2], v);
      }
      if (s < T) arriveCnt(cntG, xcls);
      // out stores (off critical path; plain cached stores, no readers)
      if (s > 1) {
        #pragma unroll
        for (int i = 0; i < 3; ++i) {
          if (Cs[i] >= 1536)
            out[(size_t)b2 * (size_t)T * 512 + (size_t)(s - 1) * 512 + (Cs[i] - 1536)] = vo[i];
        }
      }
      if (s == 1) {
        __syncthreads();                      // all Wsh reads done (reduce synced above)
        const float* src = MAz + (size_t)ch * 12288;
        #pragma unroll
        for (int i = 0; i < 6; ++i)
          ((float4*)Wsh)[tid + i * 512] = ((const float4*)src)[tid + i * 512];
        const int r0 = bid - 128;             // out[:,0,:] = inputs
        out[(size_t)r0 * (size_t)T * 512 + tid] = inputs[r0 * 512 + tid];
      }
      if (s < T) waitCnt(cntB, tgt);          // h(s+1) ready -> next step
    }
  }
}

// ======================= host launcher =======================
extern "C" void kernel_launch(void* const* d_in, const int* in_sizes, int n_in,
                              void* d_out, int out_size, void* d_ws, size_t ws_size,
                              hipStream_t stream) {
  const float* inputs = (const float*)d_in[0];
  const float* Wz = (const float*)d_in[1];
  const float* Wr = (const float*)d_in[2];
  const float* Wh = (const float*)d_in[3];
  const float* Uz = (const float*)d_in[4];
  const float* Ur = (const float*)d_in[5];
  const float* Uh = (const float*)d_in[6];
  const float* bz = (const float*)d_in[7];
  const float* br = (const float*)d_in[8];
  const float* bh = (const float*)d_in[9];
  const float* Wo = (const float*)d_in[10];
  const float* bo = (const float*)d_in[11];
  float* ws = (float*)d_ws;
  const int T = out_size / (128 * 512);

  gru_pre<<<dim3(320), dim3(256), 0, stream>>>(inputs, Wz, Wr, Wh, Uz, Ur, Uh,
                                               bz, br, bh, Wo, bo, ws);
  gru_main<<<dim3(256), dim3(512), 0, stream>>>(
      inputs, ws + OFF_MAR, ws + OFF_MAZ, ws + OFF_M1R, ws + OFF_M1Z,
      ws + OFF_UH, ws + OFF_CV, ws + OFF_C1,
      ws + OFF_H, ws + OFF_H2, ws + OFF_RH, ws + OFF_XT, ws + OFF_GZ, ws + OFF_GH,
      (uint32_t*)(ws + OFF_BAR), (float*)d_out, T);
}